// Round 12
// baseline (13553.355 us; speedup 1.0000x reference)
//
#include <hip/hip_runtime.h>
#include <cstdint>
#include <cstddef>

#define SEQ   2048
#define BATCH 64
#define HID   512

// ---------------------------------------------------------------------------
// proj GEMM: C[m][n] = sum_k A[m][k] * W[n][k] + bias[n]
// ---------------------------------------------------------------------------
__global__ __launch_bounds__(256)
void proj_gemm(const float* __restrict__ A, const float* __restrict__ W,
               const float* __restrict__ bias, float* __restrict__ C)
{
    __shared__ float As[16][132];
    __shared__ float Bs[16][132];
    const int t  = threadIdx.x;
    const int bm = blockIdx.x >> 2;
    const int bn = blockIdx.x & 3;
    const int m0 = bm * 128;
    const int n0 = bn * 128;
    const int tn = t & 15;
    const int tm = t >> 4;

    float acc[8][8];
#pragma unroll
    for (int i = 0; i < 8; ++i)
#pragma unroll
        for (int j = 0; j < 8; ++j) acc[i][j] = 0.f;

    const int lrow = t >> 2;
    const int lk4  = t & 3;

    for (int kk = 0; kk < 512; kk += 16) {
#pragma unroll
        for (int i = 0; i < 2; ++i) {
            const int row = lrow + i * 64;
            float4 va = *(const float4*)&A[(size_t)(m0 + row) * 512 + kk + lk4 * 4];
            As[lk4 * 4 + 0][row] = va.x;
            As[lk4 * 4 + 1][row] = va.y;
            As[lk4 * 4 + 2][row] = va.z;
            As[lk4 * 4 + 3][row] = va.w;
            float4 vb = *(const float4*)&W[(size_t)(n0 + row) * 512 + kk + lk4 * 4];
            Bs[lk4 * 4 + 0][row] = vb.x;
            Bs[lk4 * 4 + 1][row] = vb.y;
            Bs[lk4 * 4 + 2][row] = vb.z;
            Bs[lk4 * 4 + 3][row] = vb.w;
        }
        __syncthreads();
#pragma unroll
        for (int k = 0; k < 16; ++k) {
            float4 a0 = *(const float4*)&As[k][tm * 8];
            float4 a1 = *(const float4*)&As[k][tm * 8 + 4];
            float4 b0 = *(const float4*)&Bs[k][tn * 4];
            float4 b1 = *(const float4*)&Bs[k][64 + tn * 4];
            float ar[8] = {a0.x, a0.y, a0.z, a0.w, a1.x, a1.y, a1.z, a1.w};
            float bc[8] = {b0.x, b0.y, b0.z, b0.w, b1.x, b1.y, b1.z, b1.w};
#pragma unroll
            for (int i = 0; i < 8; ++i)
#pragma unroll
                for (int j = 0; j < 8; ++j)
                    acc[i][j] = fmaf(ar[i], bc[j], acc[i][j]);
        }
        __syncthreads();
    }

    float4 bv0 = *(const float4*)&bias[n0 + tn * 4];
    float4 bv1 = *(const float4*)&bias[n0 + 64 + tn * 4];
    const float bb[8] = {bv0.x, bv0.y, bv0.z, bv0.w, bv1.x, bv1.y, bv1.z, bv1.w};
#pragma unroll
    for (int i = 0; i < 8; ++i) {
        const size_t rowoff = (size_t)(m0 + tm * 8 + i) * 512 + n0;
        float4 o0, o1;
        o0.x = acc[i][0] + bb[0]; o0.y = acc[i][1] + bb[1];
        o0.z = acc[i][2] + bb[2]; o0.w = acc[i][3] + bb[3];
        o1.x = acc[i][4] + bb[4]; o1.y = acc[i][5] + bb[5];
        o1.z = acc[i][6] + bb[6]; o1.w = acc[i][7] + bb[7];
        *(float4*)&C[rowoff + tn * 4] = o0;
        *(float4*)&C[rowoff + 64 + tn * 4] = o1;
    }
}

// f32 -> bf16 (round to nearest even)
__device__ __forceinline__ unsigned short f2bf(float f)
{
    const unsigned int u = __float_as_uint(f);
    return (unsigned short)((u + 0x7fffu + ((u >> 16) & 1u)) >> 16);
}

// Convert W_hh (f32 [512][512] row-major) into bf16 ushort4 slots:
// slot[(kq*16 + j2)*512 + row] = bf16 of W[row][kq*64 + j2*4 .. +4)
// (kq in [0,8), j2 in [0,16)) -> in-scan loads of 8B per (kq,j2,row) are
// contiguous 64B per 8 consecutive rows.
__global__ __launch_bounds__(256)
void conv_bf16(const float* __restrict__ W, ushort4* __restrict__ dst)
{
    const int i   = blockIdx.x * 256 + threadIdx.x;   // 65536 slots
    const int row = i & 511;
    const int kj  = i >> 9;                           // kq*16 + j2
    const int k0  = ((kj >> 4) << 6) | ((kj & 15) << 2);
    const float4 v = *(const float4*)&W[(size_t)row * 512 + k0];
    ushort4 o;
    o.x = f2bf(v.x); o.y = f2bf(v.y); o.z = f2bf(v.z); o.w = f2bf(v.w);
    dst[i] = o;
}

// fast tanh: 1 - 2/(exp2(2*log2e*x)+1); exact at +/-inf, ~1e-6 abs error
__device__ __forceinline__ float fast_tanh(float x)
{
    const float e = __builtin_amdgcn_exp2f(x * 2.88539008177793f);
    return fmaf(-2.0f, __builtin_amdgcn_rcpf(e + 1.0f), 1.0f);
}

// ---------------------------------------------------------------------------
// Recurrent scan. 256 WGs x 512 thr (1 WG/CU). Group g (32) = batch pair
// (2g, 2g+1); 8 slice-WGs (bid = g + 32s, same XCD); slice owns rows
// [64s, 64s+64).
//
// W path (the round-4 L2 wall, shrunk 4x): W_hh pre-converted to bf16 and
// STREAMED FROM L2 every step via 16 volatile inline-asm global_load_dwordx2
// issued BEFORE the poll spin. Volatile asm cannot be rematerialized or sunk
// (rounds 5/11 failure mode), so the stream flies under the sync RT; the
// barrier's vmcnt(0) drain guarantees arrival before use. Per-XCD L2 traffic:
// 4 groups x 512 KB = 2 MB/step (~0.5 us) vs round 4's 8 MB (~1.9 us).
// Each W byte feeds BOTH batch elems of the group.
//
// Thread map: wave w = t>>6, l = t&63: row = 64s + w*8 + (l&7),
// k-chunk kq = l>>3 (64 k). Intra-wave butterfly (xor 8/16/32) reduces over
// kq; publishers l<16 (kc = l>>3 in {0,1} selects batch elem).
// h: LDS broadcast, 17-float4-pad layout (conflict-free, round 9).
// Sync: tagged-u64 relaxed agent atomics, s_sleep poll, parity double-buffer,
// self-routed own rows, ONE barrier/step (proof rounds 2-9).
// ---------------------------------------------------------------------------
#define WISSUE(i) asm volatile("global_load_dwordx2 %0, %1, off" \
                               : "=v"(wv##i) : "v"(wb + (i) * 512))
#define WFMA(i, accA, accB) do { \
    const float4 ha = h0[i]; const float4 hb = h1[i]; \
    const float f0 = __uint_as_float(wv##i.x << 16); \
    const float f1 = __uint_as_float(wv##i.x & 0xffff0000u); \
    const float f2 = __uint_as_float(wv##i.y << 16); \
    const float f3 = __uint_as_float(wv##i.y & 0xffff0000u); \
    accA = fmaf(f0, ha.x, accA); accA = fmaf(f1, ha.y, accA); \
    accA = fmaf(f2, ha.z, accA); accA = fmaf(f3, ha.w, accA); \
    accB = fmaf(f0, hb.x, accB); accB = fmaf(f1, hb.y, accB); \
    accB = fmaf(f2, hb.z, accB); accB = fmaf(f3, hb.w, accB); } while (0)

__global__ __launch_bounds__(512, 2)
void rnn_scan(const float* __restrict__ proj, const ushort4* __restrict__ Wbf,
              const float* __restrict__ bhh, float* __restrict__ out,
              float* __restrict__ hidden, unsigned long long* __restrict__ hbuf)
{
    __shared__ float hSf[2176];              // [p][elem][136 float4] 17-pad
    float4* hS4 = (float4*)hSf;

    const int t    = threadIdx.x;
    const int bid  = blockIdx.x;
    const int g    = bid & 31;               // group = batch pair
    const int s    = bid >> 5;               // slice 0..7 (same XCD)
    const int b0   = g * 2;
    const int base = s * 64;
    const int w    = t >> 6;                 // wave 0..7
    const int l    = t & 63;
    const int rr   = l & 7;                  // row-in-wave
    const int kq   = l >> 3;                 // k-chunk 0..7 (64 k each)
    const int row  = base + w * 8 + rr;      // output row (64 per WG)

    const bool pub  = (kq < 2);
    const float breg = pub ? bhh[row] : 0.f;

    // init both h parities to 0 (= h_init; also covers step-0 self-route)
    for (int i = t; i < 2176; i += 512) hSf[i] = 0.f;
    __syncthreads();

    const bool own  = (t >= base) && (t < base + 64);   // hid t self-routed
    const int  pado = (t >> 6) * 68 + (t & 63);         // padded scalar offset

    float pv_next = 0.f;
    if (pub) pv_next = proj[(size_t)(b0 + kq) * HID + row];

    unsigned long long* gb = hbuf + (size_t)g * 4096;   // [p][b][512] u64
    const ushort4* wb = Wbf + (size_t)(kq << 4) * 512 + row;  // + j2*512

    for (int step = 0; step < SEQ; ++step) {
        const int p = step & 1;

        const float pv = pv_next;
        if (pub && step + 1 < SEQ)
            pv_next = proj[((size_t)(step + 1) * BATCH + (b0 + kq)) * HID + row];

        // ---- issue the W bf16 stream (volatile asm: can't be sunk). The
        //      loads land during the poll spin; barrier drains vmcnt(0). ----
        uint2 wv0, wv1, wv2, wv3, wv4, wv5, wv6, wv7;
        uint2 wv8, wv9, wv10, wv11, wv12, wv13, wv14, wv15;
        WISSUE(0);  WISSUE(1);  WISSUE(2);  WISSUE(3);
        WISSUE(4);  WISSUE(5);  WISSUE(6);  WISSUE(7);
        WISSUE(8);  WISSUE(9);  WISSUE(10); WISSUE(11);
        WISSUE(12); WISSUE(13); WISSUE(14); WISSUE(15);

        // ---- poll 2 tagged u64 (hid t, batch 0/1), stage into hS[p] ----
        if (!own) {
            const unsigned int want = (unsigned int)step;
            const unsigned long long* f0 = gb + (size_t)p * 2048 + t;
            const unsigned long long* f1 = f0 + 512;
            unsigned long long x0 = 0, x1 = 0;
            bool ok0 = false, ok1 = false;
            int spins = 0;
            for (;;) {
                if (!ok0) {
                    x0 = __hip_atomic_load(f0, __ATOMIC_RELAXED, __HIP_MEMORY_SCOPE_AGENT);
                    ok0 = (unsigned int)(x0 >> 32) == want;
                }
                if (!ok1) {
                    x1 = __hip_atomic_load(f1, __ATOMIC_RELAXED, __HIP_MEMORY_SCOPE_AGENT);
                    ok1 = (unsigned int)(x1 >> 32) == want;
                }
                if (ok0 & ok1) break;
                __builtin_amdgcn_s_sleep(1);
                if (++spins > 4096) {              // hang-proofing only
                    __builtin_amdgcn_fence(__ATOMIC_ACQUIRE, "agent");
                    spins = 0;
                }
            }
            hSf[p * 1088 + pado]       = __uint_as_float((unsigned int)x0);
            hSf[p * 1088 + 544 + pado] = __uint_as_float((unsigned int)x1);
        }
        __syncthreads();   // the ONLY barrier per step (drains vmcnt too)

        // ---- matvec: streamed bf16 W regs x broadcast h (padded) ----
        const float4* h0 = hS4 + p * 272 + kq * 17;
        const float4* h1 = h0 + 136;
        float a0e = 0.f, a0o = 0.f, a1e = 0.f, a1o = 0.f;
        WFMA(0,  a0e, a1e); WFMA(1,  a0o, a1o);
        WFMA(2,  a0e, a1e); WFMA(3,  a0o, a1o);
        WFMA(4,  a0e, a1e); WFMA(5,  a0o, a1o);
        WFMA(6,  a0e, a1e); WFMA(7,  a0o, a1o);
        WFMA(8,  a0e, a1e); WFMA(9,  a0o, a1o);
        WFMA(10, a0e, a1e); WFMA(11, a0o, a1o);
        WFMA(12, a0e, a1e); WFMA(13, a0o, a1o);
        WFMA(14, a0e, a1e); WFMA(15, a0o, a1o);
        float s0 = a0e + a0o;
        float s1 = a1e + a1o;
        // butterfly over the kq bits (l^8, l^16, l^32): all lanes get totals
        s0 += __shfl_xor(s0, 8, 64);  s1 += __shfl_xor(s1, 8, 64);
        s0 += __shfl_xor(s0, 16, 64); s1 += __shfl_xor(s1, 16, 64);
        s0 += __shfl_xor(s0, 32, 64); s1 += __shfl_xor(s1, 32, 64);

        // ---- tanh + publish (kq==0 -> batch b0, kq==1 -> b0+1) ----
        if (pub) {
            const float sum = (kq == 0) ? s0 : s1;
            const int   bb  = b0 + kq;
            const float hn  = fast_tanh(pv + breg + sum);
            out[((size_t)step * BATCH + bb) * HID + row] = hn;
            const unsigned long long pk =
                ((unsigned long long)(unsigned int)(step + 1) << 32) |
                (unsigned long long)__float_as_uint(hn);
            __hip_atomic_store(gb + (size_t)(p ^ 1) * 2048 + (size_t)kq * 512 + row,
                               pk, __ATOMIC_RELAXED, __HIP_MEMORY_SCOPE_AGENT);
            hSf[(p ^ 1) * 1088 + kq * 544 + (row >> 6) * 68 + (row & 63)] = hn;
            if (step == SEQ - 1) hidden[(size_t)bb * HID + row] = hn;
        }
        // no trailing barrier: next step's pre-barrier LDS writes touch only
        // parity p^1 (disjoint from this step's hS[p] reads); hS[p] can only
        // be overwritten after the NEXT barrier.
    }
}

// ---------------------------------------------------------------------------
extern "C" void kernel_launch(void* const* d_in, const int* in_sizes, int n_in,
                              void* d_out, int out_size, void* d_ws, size_t ws_size,
                              hipStream_t stream)
{
    (void)in_sizes; (void)n_in; (void)out_size; (void)ws_size;

    const float* x    = (const float*)d_in[0];
    const float* Wih0 = (const float*)d_in[1];
    const float* Whh0 = (const float*)d_in[2];
    const float* bih0 = (const float*)d_in[3];
    const float* bhh0 = (const float*)d_in[4];
    const float* Wih1 = (const float*)d_in[5];
    const float* Whh1 = (const float*)d_in[6];
    const float* bih1 = (const float*)d_in[7];
    const float* bhh1 = (const float*)d_in[8];

    float* out1   = (float*)d_out;                        // [S][B][H]
    float* hidden = out1 + (size_t)SEQ * BATCH * HID;     // [2][B][H]

    float* proj = (float*)d_ws;                           // [S][B][H] f32
    unsigned long long* hbufA = (unsigned long long*)(proj + (size_t)SEQ * BATCH * HID);
    unsigned long long* hbufB = hbufA + (size_t)32 * 4096;
    ushort4* Wbf0 = (ushort4*)(hbufB + (size_t)32 * 4096);   // 65536 slots
    ushort4* Wbf1 = Wbf0 + 65536;

    // zero both layers' tag arrays (tag 0 == epoch 0, h = 0)
    hipMemsetAsync(hbufA, 0, (size_t)2 * 32 * 4096 * sizeof(unsigned long long),
                   stream);

    // one-time bf16 conversion of both W_hh
    conv_bf16<<<dim3(256), dim3(256), 0, stream>>>(Whh0, Wbf0);
    conv_bf16<<<dim3(256), dim3(256), 0, stream>>>(Whh1, Wbf1);

    // ---- layer 0 ----
    proj_gemm<<<dim3(4096), dim3(256), 0, stream>>>(x, Wih0, bih0, proj);
    {
        const float* p = proj; const ushort4* wv = Wbf0; const float* bb = bhh0;
        float* o = out1; float* hd = hidden; unsigned long long* hb = hbufA;
        void* args[] = {&p, &wv, &bb, &o, &hd, &hb};
        hipLaunchCooperativeKernel((const void*)rnn_scan, dim3(256), dim3(512),
                                   args, 0, stream);
    }

    // ---- layer 1 (out0 staged in d_out's out1 region) ----
    proj_gemm<<<dim3(4096), dim3(256), 0, stream>>>(out1, Wih1, bih1, proj);
    {
        const float* p = proj; const ushort4* wv = Wbf1; const float* bb = bhh1;
        float* o = out1; float* hd = hidden + BATCH * HID; unsigned long long* hb = hbufB;
        void* args[] = {&p, &wv, &bb, &o, &hd, &hb};
        hipLaunchCooperativeKernel((const void*)rnn_scan, dim3(256), dim3(512),
                                   args, 0, stream);
    }
}